// Round 2
// baseline (301.916 us; speedup 1.0000x reference)
//
#include <hip/hip_runtime.h>
#include <math.h>

#define BATCH 32768
#define NCLS  2048
#define BLOCK 256
#define GRID  (BATCH / BLOCK)  // 128

// Fused kernel: one thread per row for the cheap (t != 0) path; rows with
// t == 0 collected per-block in LDS and processed cooperatively. Block
// partials go to a global accumulator; the last block to finish writes the
// final mean (last-block-done pattern) — no separate finalize dispatch.
__global__ __launch_bounds__(BLOCK) void mpl_main(const float* __restrict__ x,
                                                  const int* __restrict__ tgt,
                                                  float* __restrict__ out,
                                                  float* __restrict__ acc,
                                                  unsigned int* __restrict__ done) {
    __shared__ int   zlist[BLOCK];
    __shared__ int   zcnt;
    __shared__ float red[BLOCK / 64];

    if (threadIdx.x == 0) zcnt = 0;
    __syncthreads();

    const int row = blockIdx.x * BLOCK + threadIdx.x;  // BATCH % BLOCK == 0
    const size_t rowbase = (size_t)row * NCLS;

    // Issue tgt and x0 loads concurrently (x0 doesn't depend on t).
    const int   t  = tgt[row];
    const float x0 = x[rowbase];

    float li = 0.0f;
    if (t != 0) {
        // negative set = {class 0}; loss = log(e^{x0} + e^{xt}) - xt = log1p(e^{x0-xt})
        const float xt = x[rowbase + t];
        li = log1pf(expf(x0 - xt));
    } else {
        zlist[atomicAdd(&zcnt, 1)] = row;
    }

    // block-reduce the cheap-path losses
    #pragma unroll
    for (int o = 32; o > 0; o >>= 1) li += __shfl_down(li, o, 64);
    const int lane = threadIdx.x & 63;
    const int wv   = threadIdx.x >> 6;
    if (lane == 0) red[wv] = li;
    __syncthreads();

    float block_sum = 0.0f;
    if (threadIdx.x == 0) {
        #pragma unroll
        for (int w = 0; w < BLOCK / 64; ++w) block_sum += red[w];
    }
    __syncthreads();  // red[] about to be reused

    // expensive path: full-row exp-sum for each t == 0 row (rare, ~16/32768)
    const int n = zcnt;
    for (int k = 0; k < n; ++k) {
        const int zr = zlist[k];
        const float4* xr = (const float4*)(x + (size_t)zr * NCLS);
        float s = 0.0f;
        #pragma unroll
        for (int j = threadIdx.x; j < NCLS / 4; j += BLOCK) {
            const float4 v = xr[j];
            s += expf(v.x) + expf(v.y) + expf(v.z) + expf(v.w);
        }
        #pragma unroll
        for (int o = 32; o > 0; o >>= 1) s += __shfl_down(s, o, 64);
        if (lane == 0) red[wv] = s;
        __syncthreads();
        if (threadIdx.x == 0) {
            float tot = 0.0f;
            #pragma unroll
            for (int w = 0; w < BLOCK / 64; ++w) tot += red[w];
            // loss = log(neg_sum + e^{x0}) - x0 = log(full_sum) - x0
            block_sum += logf(tot) - x[(size_t)zr * NCLS];
        }
        __syncthreads();  // red[] reuse next iteration
    }

    if (threadIdx.x == 0) {
        atomicAdd(acc, block_sum);          // device-scope by default
        __threadfence();                    // acc add visible before done tick
        const unsigned int old = atomicAdd(done, 1u);
        if (old == GRID - 1) {
            __threadfence();
            const float tot = atomicAdd(acc, 0.0f);  // coherent read of total
            out[0] = tot * (1.0f / (float)BATCH);
        }
    }
}

extern "C" void kernel_launch(void* const* d_in, const int* in_sizes, int n_in,
                              void* d_out, int out_size, void* d_ws, size_t ws_size,
                              hipStream_t stream) {
    const float* x   = (const float*)d_in[0];
    const int*   tgt = (const int*)d_in[1];
    float*        out  = (float*)d_out;
    float*        acc  = (float*)d_ws;
    unsigned int* done = (unsigned int*)((char*)d_ws + sizeof(float));

    hipMemsetAsync(d_ws, 0, 2 * sizeof(float), stream);
    mpl_main<<<GRID, BLOCK, 0, stream>>>(x, tgt, out, acc, done);
}